// Round 10
// baseline (665.549 us; speedup 1.0000x reference)
//
#include <hip/hip_runtime.h>
#include <hip/hip_fp16.h>

#define N_USERS 100000
#define N_ITEMS 50000
#define N_NODES 150000
#define D 64
#define NNZ 2000000
#define BATCH 256
#define POP_BINS 10

#define H_EPB 2048         // edges per block in hist/scatter
#define H_BLOCKS 978       // ceil(NNZ/H_EPB)
#define CLAIM_BLOCKS 587   // 586 scan blocks (586*256 >= 150000) + 1 flags

#define ST_P 130           // I-tile LDS pad for transposed stages

// ---------------- prep: emb->fp16 table (blocks 0..9374) + pop rows (9375) --
__global__ __launch_bounds__(256) void k_prep(const float* __restrict__ ue,
                                              const float* __restrict__ ie,
                                              __half* __restrict__ Eh,
                                              const float* __restrict__ pop,
                                              const float* __restrict__ gW1,
                                              const float* __restrict__ iW1,
                                              float* __restrict__ hp,
                                              float* __restrict__ pp1) {
  int b = blockIdx.x;
  if (b == 9375) {  // hp[b]=p_b@gW1_pop, pp1[b]=p_b@iW1
    for (int idx = threadIdx.x; idx < 2 * POP_BINS * 64; idx += 256) {
      int q = idx;
      bool second = q >= POP_BINS * 64;
      if (second) q -= POP_BINS * 64;
      int bb = q >> 6, o = q & 63;
      float s = 0.f;
      if (!second) {
        for (int k = 0; k < 64; k++) s += pop[bb * 64 + k] * gW1[(64 + k) * 64 + o];
        hp[q] = s;
      } else {
        for (int k = 0; k < 64; k++) s += pop[bb * 64 + k] * iW1[k * 64 + o];
        pp1[q] = s;
      }
    }
    return;
  }
  int t = b * 256 + threadIdx.x;     // float4 index, < 2,400,000
  size_t fo = (size_t)t * 4;
  const float* src = (fo < (size_t)N_USERS * 64) ? ue + fo
                                                 : ie + (fo - (size_t)N_USERS * 64);
  float4 v = *(const float4*)src;
  __half2* dst = (__half2*)(Eh + fo);
  dst[0] = __floats2half2_rn(v.x, v.y);
  dst[1] = __floats2half2_rn(v.z, v.w);
}

// ---------------- hist: per-row edge counts (rtmp zeroed beforehand) --------
__global__ __launch_bounds__(256) void k_hist(const int* __restrict__ rows,
                                              int* __restrict__ rtmp) {
  int base = blockIdx.x * H_EPB;
  int t = threadIdx.x;
  for (int i = 0; i < 8; i++) {
    int e = base + i * 256 + t;
    if (e < NNZ) atomicAdd(&rtmp[rows[e]], 1);
  }
}

// ---------------- claim: wave-aggregated range claim -> rowbeg/rowend -------
// One wave scans 64 row-counts (shfl inclusive scan), lane 63 claims the
// wave total with a single gcursor atomic (2344 total), rtmp becomes rowcur.
// Block CLAIM_BLOCKS-1 does the batch-user flag/dedup instead.
__global__ __launch_bounds__(256) void k_claim(int* __restrict__ rtmp,
                                               int* __restrict__ rowbeg,
                                               int* __restrict__ rowend,
                                               int* __restrict__ gcursor,
                                               const int* __restrict__ users,
                                               int* __restrict__ uflag,
                                               int* __restrict__ ulist,
                                               int* __restrict__ ucnt) {
  int t = threadIdx.x;
  if (blockIdx.x == CLAIM_BLOCKS - 1) {  // batch-user flags + unique list
    if (t < BATCH) {
      int u = users[t];
      int old = atomicOr(&uflag[u >> 5], 1 << (u & 31));
      if (!((old >> (u & 31)) & 1)) {
        int p = atomicAdd(ucnt, 1);
        ulist[p] = u;
      }
    }
    return;
  }
  int lane = t & 63;
  int row = blockIdx.x * 256 + (t >> 6) * 64 + lane;
  int c = (row < N_NODES) ? rtmp[row] : 0;
  int incl = c;
#pragma unroll
  for (int off = 1; off < 64; off <<= 1) {
    int x = __shfl_up(incl, off, 64);
    if (lane >= off) incl += x;
  }
  int total = __shfl(incl, 63, 64);
  int basev = 0;
  if (lane == 63) basev = atomicAdd(gcursor, total);
  int base = __shfl(basev, 63, 64);
  int beg = base + incl - c;
  if (row < N_NODES) {
    rowbeg[row] = beg;
    rowend[row] = beg + c;
    rtmp[row] = beg;   // becomes rowcur for k_scatter
  }
}

// ---------------- scatter: edges -> row-contiguous epack --------------------
__global__ __launch_bounds__(256) void k_scatter(const int* __restrict__ rows,
                                                 const int* __restrict__ cols,
                                                 const float* __restrict__ vals,
                                                 int* __restrict__ rtmp,  // rowcur
                                                 uint2* __restrict__ epack) {
  int base = blockIdx.x * H_EPB;
  int t = threadIdx.x;
  for (int i = 0; i < 8; i++) {
    int e = base + i * 256 + t;
    if (e < NNZ) {
      int r = rows[e];
      int pos = atomicAdd(&rtmp[r], 1);
      epack[pos] = make_uint2((unsigned)cols[e], __float_as_uint(vals[e]));
    }
  }
}

// ============ quarter-wave SPMM core (round-5 body: measured fastest) =======
#define SPMM_QW_BODY(TBL)                                                     \
  float a0 = 0.f, a1 = 0.f, a2 = 0.f, a3 = 0.f;                               \
  int j = beg;                                                                \
  for (; j + 7 < end; j += 8) {                                               \
    uint2 ea = epack[j + q];                                                  \
    uint2 eb = epack[j + 4 + q];                                              \
    uint2 ra = *(const uint2*)(TBL + (size_t)ea.x * 64 + 4 * p);              \
    uint2 rb = *(const uint2*)(TBL + (size_t)eb.x * 64 + 4 * p);              \
    float va = __uint_as_float(ea.y), vb = __uint_as_float(eb.y);             \
    float2 la = __half22float2(*(const __half2*)&ra.x);                       \
    float2 ha = __half22float2(*(const __half2*)&ra.y);                       \
    float2 lb = __half22float2(*(const __half2*)&rb.x);                       \
    float2 hb = __half22float2(*(const __half2*)&rb.y);                       \
    a0 += va * la.x; a1 += va * la.y; a2 += va * ha.x; a3 += va * ha.y;       \
    a0 += vb * lb.x; a1 += vb * lb.y; a2 += vb * hb.x; a3 += vb * hb.y;       \
  }                                                                           \
  for (; j < end; j += 4) {                                                   \
    int jj = j + q;                                                           \
    int jc = (jj < end) ? jj : end - 1;                                       \
    uint2 e = epack[jc];                                                      \
    float v = (jj < end) ? __uint_as_float(e.y) : 0.f;                        \
    uint2 r = *(const uint2*)(TBL + (size_t)e.x * 64 + 4 * p);                \
    float2 lo = __half22float2(*(const __half2*)&r.x);                        \
    float2 hi = __half22float2(*(const __half2*)&r.y);                        \
    a0 += v * lo.x; a1 += v * lo.y; a2 += v * hi.x; a3 += v * hi.y;           \
  }                                                                           \
  a0 += __shfl_xor(a0, 16, 64); a0 += __shfl_xor(a0, 32, 64);                 \
  a1 += __shfl_xor(a1, 16, 64); a1 += __shfl_xor(a1, 32, 64);                 \
  a2 += __shfl_xor(a2, 16, 64); a2 += __shfl_xor(a2, 32, 64);                 \
  a3 += __shfl_xor(a3, 16, 64); a3 += __shfl_xor(a3, 32, 64);

// ---------------- SPMM layer 1 ----------------------------------------------
__global__ __launch_bounds__(256) void k_spmm1(const int* __restrict__ rowbeg,
                                               const int* __restrict__ rowend,
                                               const uint2* __restrict__ epack,
                                               const float* __restrict__ ue,
                                               const float* __restrict__ ie,
                                               const __half* __restrict__ Eh0,
                                               const int* __restrict__ uflag,
                                               __half* __restrict__ EoutH,
                                               float* __restrict__ Oacc) {
  int wave = blockIdx.x * 4 + (threadIdx.x >> 6);
  int row = __builtin_amdgcn_readfirstlane(wave);
  if (row >= N_NODES) return;
  int lane = threadIdx.x & 63;
  int p = lane & 15, q = lane >> 4;
  int beg = rowbeg[row];
  int end = rowend[row];
  SPMM_QW_BODY(Eh0)
  if (q == 0) {
    __half2* eo = (__half2*)(EoutH + (size_t)row * 64 + 4 * p);
    eo[0] = __floats2half2_rn(a0, a1);
    eo[1] = __floats2half2_rn(a2, a3);
    bool need = (row >= N_USERS) || (((uflag[row >> 5] >> (row & 31)) & 1) != 0);
    if (need) {
      const float* srow = (row < N_USERS) ? ue + (size_t)row * 64
                                          : ie + (size_t)(row - N_USERS) * 64;
      float4 sv = *(const float4*)(srow + 4 * p);
      *(float4*)(Oacc + (size_t)row * 64 + 4 * p) =
          make_float4(0.25f * (sv.x + a0), 0.25f * (sv.y + a1),
                      0.25f * (sv.z + a2), 0.25f * (sv.w + a3));
    }
  }
}

// ---------------- SPMM layer 2 ----------------------------------------------
__global__ __launch_bounds__(256) void k_spmm2h(const int* __restrict__ rowbeg,
                                                const int* __restrict__ rowend,
                                                const uint2* __restrict__ epack,
                                                const __half* __restrict__ Ein,
                                                const int* __restrict__ uflag,
                                                __half* __restrict__ EoutH,
                                                float* __restrict__ Oacc) {
  int wave = blockIdx.x * 4 + (threadIdx.x >> 6);
  int row = __builtin_amdgcn_readfirstlane(wave);
  if (row >= N_NODES) return;
  int lane = threadIdx.x & 63;
  int p = lane & 15, q = lane >> 4;
  int beg = rowbeg[row];
  int end = rowend[row];
  SPMM_QW_BODY(Ein)
  if (q == 0) {
    __half2* eo = (__half2*)(EoutH + (size_t)row * 64 + 4 * p);
    eo[0] = __floats2half2_rn(a0, a1);
    eo[1] = __floats2half2_rn(a2, a3);
    if (row >= N_USERS || (((uflag[row >> 5] >> (row & 31)) & 1) != 0)) {
      float4* op = (float4*)(Oacc + (size_t)row * 64 + 4 * p);
      float4 cur = *op;
      *op = make_float4(cur.x + 0.25f * a0, cur.y + 0.25f * a1,
                        cur.z + 0.25f * a2, cur.w + 0.25f * a3);
    }
  }
}

// ---------------- SPMM layer 3: only needed rows ----------------------------
__global__ __launch_bounds__(256) void k_spmm3h(const int* __restrict__ rowbeg,
                                                const int* __restrict__ rowend,
                                                const uint2* __restrict__ epack,
                                                const __half* __restrict__ Ein,
                                                const int* __restrict__ ulist,
                                                const int* __restrict__ ucnt,
                                                float* __restrict__ Oacc) {
  int w = blockIdx.x * 4 + (threadIdx.x >> 6);
  int row;
  if (w < N_ITEMS) {
    row = N_USERS + w;
  } else {
    int k = w - N_ITEMS;
    if (k >= ucnt[0]) return;
    row = ulist[k];
  }
  row = __builtin_amdgcn_readfirstlane(row);
  int lane = threadIdx.x & 63;
  int p = lane & 15, q = lane >> 4;
  int beg = rowbeg[row];
  int end = rowend[row];
  SPMM_QW_BODY(Ein)
  if (q == 0) {
    float4* op = (float4*)(Oacc + (size_t)row * 64 + 4 * p);
    float4 cur = *op;
    *op = make_float4(cur.x + 0.25f * a0, cur.y + 0.25f * a1,
                      cur.z + 0.25f * a2, cur.w + 0.25f * a3);
  }
}

// ---------------- user MLP: one wave per user, coalesced weights ------------
__global__ __launch_bounds__(256) void k_user(const float* __restrict__ Oacc,
                                              const int* __restrict__ users,
                                              const float* __restrict__ ubias,
                                              const float* __restrict__ uW1,
                                              const float* __restrict__ ub1,
                                              const float* __restrict__ uW2,
                                              const float* __restrict__ ub2,
                                              float* __restrict__ Ut) {
  int ub = blockIdx.x * 4 + (threadIdx.x >> 6);
  int lane = threadIdx.x & 63;
  int u = users[ub];
  float x = Oacc[(size_t)u * 64 + lane];
  float h = ub1[lane];
#pragma unroll
  for (int k = 0; k < 64; k++)
    h = fmaf(__shfl(x, k, 64), uW1[k * 64 + lane], h);
  h = h > 0.f ? h : 0.f;
  float o = ub2[lane];
#pragma unroll
  for (int k = 0; k < 64; k++)
    o = fmaf(__shfl(h, k, 64), uW2[k * 64 + lane], o);
  Ut[lane * 256 + ub] = o;
  if (lane == 0) Ut[64 * 256 + ub] = ubias[u];  // BIAS_SCALE = 1.0
}

// ---------------- GEMM1+gate+GEMM2 fused: Oacc -> I  ------------------------
__global__ __launch_bounds__(256) void k_gemm12(const float* __restrict__ Oacc,
                                                const float* __restrict__ gW1,
                                                const float* __restrict__ iW1,
                                                const int* __restrict__ bins,
                                                const float* __restrict__ hp,
                                                const float* __restrict__ pp1,
                                                const float* __restrict__ gb1,
                                                const float* __restrict__ gW2,
                                                const float* __restrict__ gb2,
                                                const float* __restrict__ ib1,
                                                const float* __restrict__ iW2,
                                                const float* __restrict__ ib2,
                                                float* __restrict__ I) {
  __shared__ float Is[64 * ST_P];   // X^T, then H1^T after the z-sync
  __shared__ float Bs[64 * 128];    // [gW1|iW1], then iW2 in first 4096
  __shared__ float zp[128][9];
  __shared__ float zs[128];
  int tid = threadIdx.x;
  int i0 = blockIdx.x * 128;
  {
    int c4 = tid & 15, r0 = tid >> 4;
#pragma unroll
    for (int s = 0; s < 8; s++) {
      int r = r0 + s * 16;
      int it = i0 + r;
      float4 v = make_float4(0.f, 0.f, 0.f, 0.f);
      if (it < N_ITEMS) v = *(const float4*)(Oacc + (size_t)(N_USERS + it) * 64 + c4 * 4);
      Is[(c4 * 4 + 0) * ST_P + r] = v.x;
      Is[(c4 * 4 + 1) * ST_P + r] = v.y;
      Is[(c4 * 4 + 2) * ST_P + r] = v.z;
      Is[(c4 * 4 + 3) * ST_P + r] = v.w;
    }
  }
  for (int idx = tid; idx < 64 * 128; idx += 256) {
    int k = idx >> 7, o = idx & 127;
    Bs[idx] = (o < 64) ? gW1[k * 64 + o] : iW1[k * 64 + (o - 64)];
  }
  __syncthreads();
  int tx = tid & 15, ty = tid >> 4;
  float acc[8][8];
#pragma unroll
  for (int a = 0; a < 8; a++)
#pragma unroll
    for (int b = 0; b < 8; b++) acc[a][b] = 0.f;
  {
    const float* ip = Is + tx * 8;
    const float* wp = Bs + ty * 8;
#pragma unroll 2
    for (int k = 0; k < 64; k++) {
      float4 iv0 = *(const float4*)(ip + k * ST_P);
      float4 iv1 = *(const float4*)(ip + k * ST_P + 4);
      float4 wv0 = *(const float4*)(wp + k * 128);
      float4 wv1 = *(const float4*)(wp + k * 128 + 4);
      float iv[8] = {iv0.x, iv0.y, iv0.z, iv0.w, iv1.x, iv1.y, iv1.z, iv1.w};
      float wv[8] = {wv0.x, wv0.y, wv0.z, wv0.w, wv1.x, wv1.y, wv1.z, wv1.w};
#pragma unroll
      for (int a = 0; a < 8; a++)
#pragma unroll
        for (int b = 0; b < 8; b++) acc[a][b] += iv[a] * wv[b];
    }
  }
  int ibase = i0 + tx * 8;
  // --- gate: z partials from G half ---
  if (ty < 8) {
    int o0 = ty * 8;
#pragma unroll
    for (int a = 0; a < 8; a++) {
      int it = ibase + a;
      float p = 0.f;
      if (it < N_ITEMS) {
        int bin = bins[it];
        const float* hpr = hp + bin * 64 + o0;
#pragma unroll
        for (int b = 0; b < 8; b++) {
          float g = acc[a][b] + hpr[b] + gb1[o0 + b];
          g = g > 0.f ? g : 0.f;
          p += g * gW2[o0 + b];
        }
      }
      zp[tx * 8 + a][ty] = p;
    }
  }
  __syncthreads();   // also: everyone done reading Is/Bs
  if (tid < 128) {
    float s = gb2[0];
#pragma unroll
    for (int k = 0; k < 8; k++) s += zp[tid][k];
    zs[tid] = 1.f / (1.f + expf(-s));
  }
  __syncthreads();
  // --- T half: H1 -> LDS (reuse Is, layout [col][item]); stage iW2 -> Bs ---
  if (ty >= 8) {
    int o0 = (ty - 8) * 8;
#pragma unroll
    for (int a = 0; a < 8; a++) {
      int it = ibase + a;
      int item = tx * 8 + a;
      float z = zs[item];
      int bin = (it < N_ITEMS) ? bins[it] : 0;
      const float* ppr = pp1 + bin * 64 + o0;
#pragma unroll
      for (int b = 0; b < 8; b++) {
        float v = (1.f - z) * acc[a][b] + z * ppr[b] + ib1[o0 + b];
        Is[(o0 + b) * ST_P + item] = v > 0.f ? v : 0.f;
      }
    }
  }
  for (int idx = tid; idx < 64 * 64; idx += 256) Bs[idx] = iW2[idx];
  __syncthreads();
  // --- stage 2: I = H1 @ iW2 + ib2 (128x64, K=64) ---
  float acc2[8][4];
#pragma unroll
  for (int a = 0; a < 8; a++)
#pragma unroll
    for (int b = 0; b < 4; b++) acc2[a][b] = 0.f;
  {
    const float* ip = Is + tx * 8;
    const float* wp = Bs + ty * 4;
#pragma unroll 2
    for (int k = 0; k < 64; k++) {
      float4 iv0 = *(const float4*)(ip + k * ST_P);
      float4 iv1 = *(const float4*)(ip + k * ST_P + 4);
      float4 wv = *(const float4*)(wp + k * 64);
      float iv[8] = {iv0.x, iv0.y, iv0.z, iv0.w, iv1.x, iv1.y, iv1.z, iv1.w};
      float wvv[4] = {wv.x, wv.y, wv.z, wv.w};
#pragma unroll
      for (int a = 0; a < 8; a++)
#pragma unroll
        for (int b = 0; b < 4; b++) acc2[a][b] += iv[a] * wvv[b];
    }
  }
  int oc = ty * 4;
  float b0 = ib2[oc], b1 = ib2[oc + 1], b2 = ib2[oc + 2], b3 = ib2[oc + 3];
#pragma unroll
  for (int a = 0; a < 8; a++) {
    int it = ibase + a;
    if (it < N_ITEMS) {
      float4 s0 = make_float4(acc2[a][0] + b0, acc2[a][1] + b1,
                              acc2[a][2] + b2, acc2[a][3] + b3);
      *(float4*)(I + (size_t)it * 64 + oc) = s0;
    }
  }
}

// ---------------- scores: Is staged once, both user-halves per block --------
__global__ __launch_bounds__(256) void k_scores(const float* __restrict__ I,
                                                const float* __restrict__ Ut,
                                                const float* __restrict__ item_bias,
                                                float* __restrict__ out) {
  __shared__ float Is[64 * ST_P];
  __shared__ float Us[64 * 128];
  int tid = threadIdx.x;
  int i0 = blockIdx.x * 128;
  {
    int c4 = tid & 15, r0 = tid >> 4;
#pragma unroll
    for (int s = 0; s < 8; s++) {
      int r = r0 + s * 16;
      int it = i0 + r;
      float4 v = make_float4(0.f, 0.f, 0.f, 0.f);
      if (it < N_ITEMS) v = *(const float4*)(I + (size_t)it * 64 + c4 * 4);
      Is[(c4 * 4 + 0) * ST_P + r] = v.x;
      Is[(c4 * 4 + 1) * ST_P + r] = v.y;
      Is[(c4 * 4 + 2) * ST_P + r] = v.z;
      Is[(c4 * 4 + 3) * ST_P + r] = v.w;
    }
  }
  int tx = tid & 15;
  int ty = tid >> 4;
  int ibase = i0 + tx * 8;
  float ib[8];
#pragma unroll
  for (int a = 0; a < 8; a++)
    ib[a] = (ibase + a < N_ITEMS) ? item_bias[ibase + a] : 0.f;
  for (int uh = 0; uh < 2; uh++) {
    int ubase = uh * 128;
    if (uh) __syncthreads();   // previous Us fully consumed
    {
      int u4 = tid & 31, k0 = tid >> 5;
#pragma unroll
      for (int s = 0; s < 8; s++) {
        int k = k0 + s * 8;
        float4 v = *(const float4*)(Ut + k * 256 + ubase + u4 * 4);
        *(float4*)(Us + k * 128 + u4 * 4) = v;
      }
    }
    __syncthreads();
    float acc[8][8];
#pragma unroll
    for (int a = 0; a < 8; a++)
#pragma unroll
      for (int b = 0; b < 8; b++) acc[a][b] = 0.f;
    const float* ip = Is + tx * 8;
    const float* up = Us + ty * 8;
#pragma unroll 2
    for (int k = 0; k < 64; k++) {
      float4 iv0 = *(const float4*)(ip + k * ST_P);
      float4 iv1 = *(const float4*)(ip + k * ST_P + 4);
      float4 uv0 = *(const float4*)(up + k * 128);
      float4 uv1 = *(const float4*)(up + k * 128 + 4);
      float iv[8] = {iv0.x, iv0.y, iv0.z, iv0.w, iv1.x, iv1.y, iv1.z, iv1.w};
      float uv[8] = {uv0.x, uv0.y, uv0.z, uv0.w, uv1.x, uv1.y, uv1.z, uv1.w};
#pragma unroll
      for (int a = 0; a < 8; a++)
#pragma unroll
        for (int b = 0; b < 8; b++) acc[a][b] += iv[a] * uv[b];
    }
#pragma unroll
    for (int bb = 0; bb < 8; bb++) {
      int bu = ubase + ty * 8 + bb;
      float ubias = Ut[64 * 256 + bu];
      float* orow = out + (size_t)bu * N_ITEMS + ibase;
      if (ibase + 7 < N_ITEMS) {
        float4 s0 = make_float4(acc[0][bb] + ubias + ib[0], acc[1][bb] + ubias + ib[1],
                                acc[2][bb] + ubias + ib[2], acc[3][bb] + ubias + ib[3]);
        float4 s1 = make_float4(acc[4][bb] + ubias + ib[4], acc[5][bb] + ubias + ib[5],
                                acc[6][bb] + ubias + ib[6], acc[7][bb] + ubias + ib[7]);
        *(float4*)orow = s0;
        *(float4*)(orow + 4) = s1;
      } else {
#pragma unroll
        for (int a = 0; a < 8; a++)
          if (ibase + a < N_ITEMS) orow[a] = acc[a][bb] + ubias + ib[a];
      }
    }
  }
}

extern "C" void kernel_launch(void* const* d_in, const int* in_sizes, int n_in,
                              void* d_out, int out_size, void* d_ws, size_t ws_size,
                              hipStream_t stream) {
  const float* user_emb  = (const float*)d_in[0];
  const float* item_emb  = (const float*)d_in[1];
  const float* user_bias = (const float*)d_in[2];
  const float* item_bias = (const float*)d_in[3];
  const float* pop_emb   = (const float*)d_in[4];
  const float* uW1 = (const float*)d_in[5];
  const float* ub1 = (const float*)d_in[6];
  const float* uW2 = (const float*)d_in[7];
  const float* ub2 = (const float*)d_in[8];
  const float* iW1 = (const float*)d_in[9];
  const float* ib1 = (const float*)d_in[10];
  const float* iW2 = (const float*)d_in[11];
  const float* ib2 = (const float*)d_in[12];
  const float* gW1 = (const float*)d_in[13];
  const float* gb1 = (const float*)d_in[14];
  const float* gW2 = (const float*)d_in[15];
  const float* gb2 = (const float*)d_in[16];
  const float* adj_vals = (const float*)d_in[17];
  const int* adj_rows = (const int*)d_in[18];
  const int* adj_cols = (const int*)d_in[19];
  const int* bins  = (const int*)d_in[20];
  const int* users = (const int*)d_in[21];
  float* out = (float*)d_out;

  // workspace layout (float offsets); high-water 33,122,640
  float* ws = (float*)d_ws;
  float* Oacc = ws;                    // 9,600,000
  float* bufA = ws + 9600000;          // 9,600,000
  float* bufB = ws + 19200000;         // 9,600,000 (rtmp lives here pre-spmm2)
  uint2* epack = (uint2*)(ws + 28800000);      // 2M uint2 -> ends 32,800,000
  int* rowbeg = (int*)(ws + 32800000);         // 150,000 -> 32,950,000
  int* rowend = (int*)(ws + 32950000);         // 150,000 -> 33,100,000
  // control ints: contiguous for a single memset
  int* uflag   = (int*)(ws + 33100000);        // 3,125 (bitmask)
  int* ucnt    = (int*)(ws + 33103125);        // 1
  int* gcursor = (int*)(ws + 33103126);        // 1
  int* ulist   = (int*)(ws + 33103127);        // 256 -> ends 33,103,383
  float* Ut   = ws + 33104000;                 // 16,640 -> 33,120,640
  float* hp   = ws + 33121000;                 // 640
  float* pp1  = ws + 33122000;                 // 640
  int* rtmp = (int*)bufB;                      // 150,000 (rcnt -> rowcur); bufB
                                               // free until spmm2 writes E2h
  __half* Eh0 = (__half*)bufA;                 // emb fp16; dead after spmm1
  __half* E1h = (__half*)(bufA + 4800000);     // layer1 out; dead after spmm2
  __half* E2h = (__half*)bufB;                 // layer2 out (rtmp dead by then)
  float* I  = bufB;                            // 3,200,000 (E2h dead by then)

  hipMemsetAsync(uflag, 0, 3400 * sizeof(int), stream);    // uflag..ulist
  hipMemsetAsync(rtmp, 0, N_NODES * sizeof(int), stream);  // row counts
  k_prep<<<9376, 256, 0, stream>>>(user_emb, item_emb, Eh0, pop_emb, gW1, iW1, hp, pp1);
  k_hist<<<H_BLOCKS, 256, 0, stream>>>(adj_rows, rtmp);
  k_claim<<<CLAIM_BLOCKS, 256, 0, stream>>>(rtmp, rowbeg, rowend, gcursor,
                                            users, uflag, ulist, ucnt);
  k_scatter<<<H_BLOCKS, 256, 0, stream>>>(adj_rows, adj_cols, adj_vals, rtmp, epack);

  k_spmm1<<<37500, 256, 0, stream>>>(rowbeg, rowend, epack, user_emb, item_emb,
                                     Eh0, uflag, E1h, Oacc);
  k_spmm2h<<<37500, 256, 0, stream>>>(rowbeg, rowend, epack, E1h, uflag, E2h, Oacc);
  k_spmm3h<<<12564, 256, 0, stream>>>(rowbeg, rowend, epack, E2h, ulist, ucnt, Oacc);

  k_user<<<64, 256, 0, stream>>>(Oacc, users, user_bias, uW1, ub1, uW2, ub2, Ut);
  k_gemm12<<<391, 256, 0, stream>>>(Oacc, gW1, iW1, bins, hp, pp1, gb1, gW2, gb2,
                                    ib1, iW2, ib2, I);
  k_scores<<<391, 256, 0, stream>>>(I, Ut, item_bias, out);
}

// Round 11
// 469.124 us; speedup vs baseline: 1.4187x; 1.4187x over previous
//
#include <hip/hip_runtime.h>
#include <hip/hip_fp16.h>

#define N_USERS 100000
#define N_ITEMS 50000
#define N_NODES 150000
#define D 64
#define NNZ 2000000
#define BATCH 256
#define POP_BINS 10

// bucketed CSR params
#define BSH 9
#define NB2 293            // ceil(150000/512)
#define CAP 8192           // max edges per bucket (mean 6827, sigma ~82)
#define P1_EPB 4096        // edges per block in pass 1 (4096 measured best:
                           // 2048 -> 73us [r9], 4096 -> ~60us [r7])
#define P1_BLOCKS 489      // ceil(NNZ/P1_EPB)

#define ST_P 130           // I-tile LDS pad for transposed stages

// ---------------- prep: emb->fp16 table (blocks 0..9374) + pop rows (9375) --
__global__ __launch_bounds__(256) void k_prep(const float* __restrict__ ue,
                                              const float* __restrict__ ie,
                                              __half* __restrict__ Eh,
                                              const float* __restrict__ pop,
                                              const float* __restrict__ gW1,
                                              const float* __restrict__ iW1,
                                              float* __restrict__ hp,
                                              float* __restrict__ pp1) {
  int b = blockIdx.x;
  if (b == 9375) {  // hp[b]=p_b@gW1_pop, pp1[b]=p_b@iW1
    for (int idx = threadIdx.x; idx < 2 * POP_BINS * 64; idx += 256) {
      int q = idx;
      bool second = q >= POP_BINS * 64;
      if (second) q -= POP_BINS * 64;
      int bb = q >> 6, o = q & 63;
      float s = 0.f;
      if (!second) {
        for (int k = 0; k < 64; k++) s += pop[bb * 64 + k] * gW1[(64 + k) * 64 + o];
        hp[q] = s;
      } else {
        for (int k = 0; k < 64; k++) s += pop[bb * 64 + k] * iW1[k * 64 + o];
        pp1[q] = s;
      }
    }
    return;
  }
  int t = b * 256 + threadIdx.x;     // float4 index, < 2,400,000
  size_t fo = (size_t)t * 4;
  const float* src = (fo < (size_t)N_USERS * 64) ? ue + fo
                                                 : ie + (fo - (size_t)N_USERS * 64);
  float4 v = *(const float4*)src;
  __half2* dst = (__half2*)(Eh + fo);
  dst[0] = __floats2half2_rn(v.x, v.y);
  dst[1] = __floats2half2_rn(v.z, v.w);
}

// ---------------- pass 1: bucket edges into strided gstage ------------------
__global__ __launch_bounds__(256) void k_p1(const int* __restrict__ rows,
                                            const int* __restrict__ cols,
                                            const float* __restrict__ vals,
                                            int* __restrict__ bcur,
                                            uint2* __restrict__ gstage) {
  __shared__ int cnt[NB2];
  __shared__ int gbase[NB2];
  int t = threadIdx.x;
  for (int i = t; i < NB2; i += 256) cnt[i] = 0;
  __syncthreads();
  int base = blockIdx.x * P1_EPB;
  for (int i = 0; i < 16; i++) {
    int e = base + i * 256 + t;
    if (e < NNZ) atomicAdd(&cnt[rows[e] >> BSH], 1);
  }
  __syncthreads();
  for (int i = t; i < NB2; i += 256) {
    int c = cnt[i];
    gbase[i] = c ? atomicAdd(&bcur[i], c) : 0;
    cnt[i] = 0;
  }
  __syncthreads();
  for (int i = 0; i < 16; i++) {
    int e = base + i * 256 + t;
    if (e < NNZ) {
      int r = rows[e];
      int b = r >> BSH;
      int rank = atomicAdd(&cnt[b], 1);
      unsigned key = ((unsigned)(r & 511) << 18) | (unsigned)cols[e];
      gstage[(size_t)b * CAP + gbase[b] + rank] =
          make_uint2(key, __float_as_uint(vals[e]));
    }
  }
}

// ---------------- pass 2: 512 threads (block count fixed at 293 = 1.15/CU,
// halve per-thread serial work) (+batch flags at b==NB2) ---------------------
__global__ __launch_bounds__(512) void k_p2(const int* __restrict__ bcur,
                                            const uint2* __restrict__ gstage,
                                            uint2* __restrict__ epack,
                                            int* __restrict__ rowbeg,
                                            int* __restrict__ rowend,
                                            int* __restrict__ gcursor,
                                            const int* __restrict__ users,
                                            int* __restrict__ uflag,
                                            int* __restrict__ ulist,
                                            int* __restrict__ ucnt) {
  int b = blockIdx.x, t = threadIdx.x;
  if (b == NB2) {  // batch-user flags (bitmask) + unique list
    if (t < BATCH) {
      int u = users[t];
      int old = atomicOr(&uflag[u >> 5], 1 << (u & 31));
      if (!((old >> (u & 31)) & 1)) {
        int p = atomicAdd(ucnt, 1);
        ulist[p] = u;
      }
    }
    return;
  }
  __shared__ int cnt[512];
  __shared__ int off[512];
  __shared__ int s[512];
  __shared__ int gbs;
  __shared__ uint2 buf[CAP];
  int n = bcur[b];
  const uint2* gs = gstage + (size_t)b * CAP;
  if (t == 0) gbs = atomicAdd(gcursor, n);
  cnt[t] = 0;
  __syncthreads();
  for (int j = t; j < n; j += 512)
    atomicAdd(&cnt[gs[j].x >> 18], 1);
  __syncthreads();
  int v = cnt[t];
  s[t] = v;
  __syncthreads();
  for (int o = 1; o < 512; o <<= 1) {
    int x = (t >= o) ? s[t - o] : 0;
    __syncthreads();
    s[t] += x;
    __syncthreads();
  }
  int ex = s[t] - v;         // exclusive prefix
  off[t] = ex;
  int base = gbs;
  int gr = (b << BSH) + t;
  if (gr < N_NODES) { rowbeg[gr] = base + ex; rowend[gr] = base + ex + v; }
  __syncthreads();
  for (int j = t; j < n; j += 512) {
    uint2 ed = gs[j];
    int lr = ed.x >> 18;
    int pos = atomicAdd(&off[lr], 1);
    buf[pos] = make_uint2(ed.x & 0x3FFFFu, ed.y);
  }
  __syncthreads();
  for (int j = t; j < n; j += 512) epack[base + j] = buf[j];
}

// ============ quarter-wave SPMM core (round-5 body: measured fastest) =======
#define SPMM_QW_BODY(TBL)                                                     \
  float a0 = 0.f, a1 = 0.f, a2 = 0.f, a3 = 0.f;                               \
  int j = beg;                                                                \
  for (; j + 7 < end; j += 8) {                                               \
    uint2 ea = epack[j + q];                                                  \
    uint2 eb = epack[j + 4 + q];                                              \
    uint2 ra = *(const uint2*)(TBL + (size_t)ea.x * 64 + 4 * p);              \
    uint2 rb = *(const uint2*)(TBL + (size_t)eb.x * 64 + 4 * p);              \
    float va = __uint_as_float(ea.y), vb = __uint_as_float(eb.y);             \
    float2 la = __half22float2(*(const __half2*)&ra.x);                       \
    float2 ha = __half22float2(*(const __half2*)&ra.y);                       \
    float2 lb = __half22float2(*(const __half2*)&rb.x);                       \
    float2 hb = __half22float2(*(const __half2*)&rb.y);                       \
    a0 += va * la.x; a1 += va * la.y; a2 += va * ha.x; a3 += va * ha.y;       \
    a0 += vb * lb.x; a1 += vb * lb.y; a2 += vb * hb.x; a3 += vb * hb.y;       \
  }                                                                           \
  for (; j < end; j += 4) {                                                   \
    int jj = j + q;                                                           \
    int jc = (jj < end) ? jj : end - 1;                                       \
    uint2 e = epack[jc];                                                      \
    float v = (jj < end) ? __uint_as_float(e.y) : 0.f;                        \
    uint2 r = *(const uint2*)(TBL + (size_t)e.x * 64 + 4 * p);                \
    float2 lo = __half22float2(*(const __half2*)&r.x);                        \
    float2 hi = __half22float2(*(const __half2*)&r.y);                        \
    a0 += v * lo.x; a1 += v * lo.y; a2 += v * hi.x; a3 += v * hi.y;           \
  }                                                                           \
  a0 += __shfl_xor(a0, 16, 64); a0 += __shfl_xor(a0, 32, 64);                 \
  a1 += __shfl_xor(a1, 16, 64); a1 += __shfl_xor(a1, 32, 64);                 \
  a2 += __shfl_xor(a2, 16, 64); a2 += __shfl_xor(a2, 32, 64);                 \
  a3 += __shfl_xor(a3, 16, 64); a3 += __shfl_xor(a3, 32, 64);

// ---------------- SPMM layer 1 ----------------------------------------------
__global__ __launch_bounds__(256) void k_spmm1(const int* __restrict__ rowbeg,
                                               const int* __restrict__ rowend,
                                               const uint2* __restrict__ epack,
                                               const float* __restrict__ ue,
                                               const float* __restrict__ ie,
                                               const __half* __restrict__ Eh0,
                                               const int* __restrict__ uflag,
                                               __half* __restrict__ EoutH,
                                               float* __restrict__ Oacc) {
  int wave = blockIdx.x * 4 + (threadIdx.x >> 6);
  int row = __builtin_amdgcn_readfirstlane(wave);
  if (row >= N_NODES) return;
  int lane = threadIdx.x & 63;
  int p = lane & 15, q = lane >> 4;
  int beg = rowbeg[row];
  int end = rowend[row];
  SPMM_QW_BODY(Eh0)
  if (q == 0) {
    __half2* eo = (__half2*)(EoutH + (size_t)row * 64 + 4 * p);
    eo[0] = __floats2half2_rn(a0, a1);
    eo[1] = __floats2half2_rn(a2, a3);
    bool need = (row >= N_USERS) || (((uflag[row >> 5] >> (row & 31)) & 1) != 0);
    if (need) {
      const float* srow = (row < N_USERS) ? ue + (size_t)row * 64
                                          : ie + (size_t)(row - N_USERS) * 64;
      float4 sv = *(const float4*)(srow + 4 * p);
      *(float4*)(Oacc + (size_t)row * 64 + 4 * p) =
          make_float4(0.25f * (sv.x + a0), 0.25f * (sv.y + a1),
                      0.25f * (sv.z + a2), 0.25f * (sv.w + a3));
    }
  }
}

// ---------------- SPMM layer 2 ----------------------------------------------
__global__ __launch_bounds__(256) void k_spmm2h(const int* __restrict__ rowbeg,
                                                const int* __restrict__ rowend,
                                                const uint2* __restrict__ epack,
                                                const __half* __restrict__ Ein,
                                                const int* __restrict__ uflag,
                                                __half* __restrict__ EoutH,
                                                float* __restrict__ Oacc) {
  int wave = blockIdx.x * 4 + (threadIdx.x >> 6);
  int row = __builtin_amdgcn_readfirstlane(wave);
  if (row >= N_NODES) return;
  int lane = threadIdx.x & 63;
  int p = lane & 15, q = lane >> 4;
  int beg = rowbeg[row];
  int end = rowend[row];
  SPMM_QW_BODY(Ein)
  if (q == 0) {
    __half2* eo = (__half2*)(EoutH + (size_t)row * 64 + 4 * p);
    eo[0] = __floats2half2_rn(a0, a1);
    eo[1] = __floats2half2_rn(a2, a3);
    if (row >= N_USERS || (((uflag[row >> 5] >> (row & 31)) & 1) != 0)) {
      float4* op = (float4*)(Oacc + (size_t)row * 64 + 4 * p);
      float4 cur = *op;
      *op = make_float4(cur.x + 0.25f * a0, cur.y + 0.25f * a1,
                        cur.z + 0.25f * a2, cur.w + 0.25f * a3);
    }
  }
}

// ---------------- SPMM layer 3: only needed rows ----------------------------
__global__ __launch_bounds__(256) void k_spmm3h(const int* __restrict__ rowbeg,
                                                const int* __restrict__ rowend,
                                                const uint2* __restrict__ epack,
                                                const __half* __restrict__ Ein,
                                                const int* __restrict__ ulist,
                                                const int* __restrict__ ucnt,
                                                float* __restrict__ Oacc) {
  int w = blockIdx.x * 4 + (threadIdx.x >> 6);
  int row;
  if (w < N_ITEMS) {
    row = N_USERS + w;
  } else {
    int k = w - N_ITEMS;
    if (k >= ucnt[0]) return;
    row = ulist[k];
  }
  row = __builtin_amdgcn_readfirstlane(row);
  int lane = threadIdx.x & 63;
  int p = lane & 15, q = lane >> 4;
  int beg = rowbeg[row];
  int end = rowend[row];
  SPMM_QW_BODY(Ein)
  if (q == 0) {
    float4* op = (float4*)(Oacc + (size_t)row * 64 + 4 * p);
    float4 cur = *op;
    *op = make_float4(cur.x + 0.25f * a0, cur.y + 0.25f * a1,
                      cur.z + 0.25f * a2, cur.w + 0.25f * a3);
  }
}

// ---------------- user MLP: one wave per user, coalesced weights ------------
__global__ __launch_bounds__(256) void k_user(const float* __restrict__ Oacc,
                                              const int* __restrict__ users,
                                              const float* __restrict__ ubias,
                                              const float* __restrict__ uW1,
                                              const float* __restrict__ ub1,
                                              const float* __restrict__ uW2,
                                              const float* __restrict__ ub2,
                                              float* __restrict__ Ut) {
  int ub = blockIdx.x * 4 + (threadIdx.x >> 6);
  int lane = threadIdx.x & 63;
  int u = users[ub];
  float x = Oacc[(size_t)u * 64 + lane];
  float h = ub1[lane];
#pragma unroll
  for (int k = 0; k < 64; k++)
    h = fmaf(__shfl(x, k, 64), uW1[k * 64 + lane], h);
  h = h > 0.f ? h : 0.f;
  float o = ub2[lane];
#pragma unroll
  for (int k = 0; k < 64; k++)
    o = fmaf(__shfl(h, k, 64), uW2[k * 64 + lane], o);
  Ut[lane * 256 + ub] = o;
  if (lane == 0) Ut[64 * 256 + ub] = ubias[u];  // BIAS_SCALE = 1.0
}

// ---------------- GEMM1+gate+GEMM2 fused: Oacc -> I  ------------------------
__global__ __launch_bounds__(256) void k_gemm12(const float* __restrict__ Oacc,
                                                const float* __restrict__ gW1,
                                                const float* __restrict__ iW1,
                                                const int* __restrict__ bins,
                                                const float* __restrict__ hp,
                                                const float* __restrict__ pp1,
                                                const float* __restrict__ gb1,
                                                const float* __restrict__ gW2,
                                                const float* __restrict__ gb2,
                                                const float* __restrict__ ib1,
                                                const float* __restrict__ iW2,
                                                const float* __restrict__ ib2,
                                                float* __restrict__ I) {
  __shared__ float Is[64 * ST_P];   // X^T, then H1^T after the z-sync
  __shared__ float Bs[64 * 128];    // [gW1|iW1], then iW2 in first 4096
  __shared__ float zp[128][9];
  __shared__ float zs[128];
  int tid = threadIdx.x;
  int i0 = blockIdx.x * 128;
  {
    int c4 = tid & 15, r0 = tid >> 4;
#pragma unroll
    for (int s = 0; s < 8; s++) {
      int r = r0 + s * 16;
      int it = i0 + r;
      float4 v = make_float4(0.f, 0.f, 0.f, 0.f);
      if (it < N_ITEMS) v = *(const float4*)(Oacc + (size_t)(N_USERS + it) * 64 + c4 * 4);
      Is[(c4 * 4 + 0) * ST_P + r] = v.x;
      Is[(c4 * 4 + 1) * ST_P + r] = v.y;
      Is[(c4 * 4 + 2) * ST_P + r] = v.z;
      Is[(c4 * 4 + 3) * ST_P + r] = v.w;
    }
  }
  for (int idx = tid; idx < 64 * 128; idx += 256) {
    int k = idx >> 7, o = idx & 127;
    Bs[idx] = (o < 64) ? gW1[k * 64 + o] : iW1[k * 64 + (o - 64)];
  }
  __syncthreads();
  int tx = tid & 15, ty = tid >> 4;
  float acc[8][8];
#pragma unroll
  for (int a = 0; a < 8; a++)
#pragma unroll
    for (int b = 0; b < 8; b++) acc[a][b] = 0.f;
  {
    const float* ip = Is + tx * 8;
    const float* wp = Bs + ty * 8;
#pragma unroll 2
    for (int k = 0; k < 64; k++) {
      float4 iv0 = *(const float4*)(ip + k * ST_P);
      float4 iv1 = *(const float4*)(ip + k * ST_P + 4);
      float4 wv0 = *(const float4*)(wp + k * 128);
      float4 wv1 = *(const float4*)(wp + k * 128 + 4);
      float iv[8] = {iv0.x, iv0.y, iv0.z, iv0.w, iv1.x, iv1.y, iv1.z, iv1.w};
      float wv[8] = {wv0.x, wv0.y, wv0.z, wv0.w, wv1.x, wv1.y, wv1.z, wv1.w};
#pragma unroll
      for (int a = 0; a < 8; a++)
#pragma unroll
        for (int b = 0; b < 8; b++) acc[a][b] += iv[a] * wv[b];
    }
  }
  int ibase = i0 + tx * 8;
  // --- gate: z partials from G half ---
  if (ty < 8) {
    int o0 = ty * 8;
#pragma unroll
    for (int a = 0; a < 8; a++) {
      int it = ibase + a;
      float p = 0.f;
      if (it < N_ITEMS) {
        int bin = bins[it];
        const float* hpr = hp + bin * 64 + o0;
#pragma unroll
        for (int b = 0; b < 8; b++) {
          float g = acc[a][b] + hpr[b] + gb1[o0 + b];
          g = g > 0.f ? g : 0.f;
          p += g * gW2[o0 + b];
        }
      }
      zp[tx * 8 + a][ty] = p;
    }
  }
  __syncthreads();   // also: everyone done reading Is/Bs
  if (tid < 128) {
    float s = gb2[0];
#pragma unroll
    for (int k = 0; k < 8; k++) s += zp[tid][k];
    zs[tid] = 1.f / (1.f + expf(-s));
  }
  __syncthreads();
  // --- T half: H1 -> LDS (reuse Is, layout [col][item]); stage iW2 -> Bs ---
  if (ty >= 8) {
    int o0 = (ty - 8) * 8;
#pragma unroll
    for (int a = 0; a < 8; a++) {
      int it = ibase + a;
      int item = tx * 8 + a;
      float z = zs[item];
      int bin = (it < N_ITEMS) ? bins[it] : 0;
      const float* ppr = pp1 + bin * 64 + o0;
#pragma unroll
      for (int b = 0; b < 8; b++) {
        float v = (1.f - z) * acc[a][b] + z * ppr[b] + ib1[o0 + b];
        Is[(o0 + b) * ST_P + item] = v > 0.f ? v : 0.f;
      }
    }
  }
  for (int idx = tid; idx < 64 * 64; idx += 256) Bs[idx] = iW2[idx];
  __syncthreads();
  // --- stage 2: I = H1 @ iW2 + ib2 (128x64, K=64) ---
  float acc2[8][4];
#pragma unroll
  for (int a = 0; a < 8; a++)
#pragma unroll
    for (int b = 0; b < 4; b++) acc2[a][b] = 0.f;
  {
    const float* ip = Is + tx * 8;
    const float* wp = Bs + ty * 4;
#pragma unroll 2
    for (int k = 0; k < 64; k++) {
      float4 iv0 = *(const float4*)(ip + k * ST_P);
      float4 iv1 = *(const float4*)(ip + k * ST_P + 4);
      float4 wv = *(const float4*)(wp + k * 64);
      float iv[8] = {iv0.x, iv0.y, iv0.z, iv0.w, iv1.x, iv1.y, iv1.z, iv1.w};
      float wvv[4] = {wv.x, wv.y, wv.z, wv.w};
#pragma unroll
      for (int a = 0; a < 8; a++)
#pragma unroll
        for (int b = 0; b < 4; b++) acc2[a][b] += iv[a] * wvv[b];
    }
  }
  int oc = ty * 4;
  float b0 = ib2[oc], b1 = ib2[oc + 1], b2 = ib2[oc + 2], b3 = ib2[oc + 3];
#pragma unroll
  for (int a = 0; a < 8; a++) {
    int it = ibase + a;
    if (it < N_ITEMS) {
      float4 s0 = make_float4(acc2[a][0] + b0, acc2[a][1] + b1,
                              acc2[a][2] + b2, acc2[a][3] + b3);
      *(float4*)(I + (size_t)it * 64 + oc) = s0;
    }
  }
}

// ---------------- scores: Is staged once, both user-halves per block --------
__global__ __launch_bounds__(256) void k_scores(const float* __restrict__ I,
                                                const float* __restrict__ Ut,
                                                const float* __restrict__ item_bias,
                                                float* __restrict__ out) {
  __shared__ float Is[64 * ST_P];
  __shared__ float Us[64 * 128];
  int tid = threadIdx.x;
  int i0 = blockIdx.x * 128;
  {
    int c4 = tid & 15, r0 = tid >> 4;
#pragma unroll
    for (int s = 0; s < 8; s++) {
      int r = r0 + s * 16;
      int it = i0 + r;
      float4 v = make_float4(0.f, 0.f, 0.f, 0.f);
      if (it < N_ITEMS) v = *(const float4*)(I + (size_t)it * 64 + c4 * 4);
      Is[(c4 * 4 + 0) * ST_P + r] = v.x;
      Is[(c4 * 4 + 1) * ST_P + r] = v.y;
      Is[(c4 * 4 + 2) * ST_P + r] = v.z;
      Is[(c4 * 4 + 3) * ST_P + r] = v.w;
    }
  }
  int tx = tid & 15;
  int ty = tid >> 4;
  int ibase = i0 + tx * 8;
  float ib[8];
#pragma unroll
  for (int a = 0; a < 8; a++)
    ib[a] = (ibase + a < N_ITEMS) ? item_bias[ibase + a] : 0.f;
  for (int uh = 0; uh < 2; uh++) {
    int ubase = uh * 128;
    if (uh) __syncthreads();   // previous Us fully consumed
    {
      int u4 = tid & 31, k0 = tid >> 5;
#pragma unroll
      for (int s = 0; s < 8; s++) {
        int k = k0 + s * 8;
        float4 v = *(const float4*)(Ut + k * 256 + ubase + u4 * 4);
        *(float4*)(Us + k * 128 + u4 * 4) = v;
      }
    }
    __syncthreads();
    float acc[8][8];
#pragma unroll
    for (int a = 0; a < 8; a++)
#pragma unroll
      for (int b = 0; b < 8; b++) acc[a][b] = 0.f;
    const float* ip = Is + tx * 8;
    const float* up = Us + ty * 8;
#pragma unroll 2
    for (int k = 0; k < 64; k++) {
      float4 iv0 = *(const float4*)(ip + k * ST_P);
      float4 iv1 = *(const float4*)(ip + k * ST_P + 4);
      float4 uv0 = *(const float4*)(up + k * 128);
      float4 uv1 = *(const float4*)(up + k * 128 + 4);
      float iv[8] = {iv0.x, iv0.y, iv0.z, iv0.w, iv1.x, iv1.y, iv1.z, iv1.w};
      float uv[8] = {uv0.x, uv0.y, uv0.z, uv0.w, uv1.x, uv1.y, uv1.z, uv1.w};
#pragma unroll
      for (int a = 0; a < 8; a++)
#pragma unroll
        for (int b = 0; b < 8; b++) acc[a][b] += iv[a] * uv[b];
    }
#pragma unroll
    for (int bb = 0; bb < 8; bb++) {
      int bu = ubase + ty * 8 + bb;
      float ubias = Ut[64 * 256 + bu];
      float* orow = out + (size_t)bu * N_ITEMS + ibase;
      if (ibase + 7 < N_ITEMS) {
        float4 s0 = make_float4(acc[0][bb] + ubias + ib[0], acc[1][bb] + ubias + ib[1],
                                acc[2][bb] + ubias + ib[2], acc[3][bb] + ubias + ib[3]);
        float4 s1 = make_float4(acc[4][bb] + ubias + ib[4], acc[5][bb] + ubias + ib[5],
                                acc[6][bb] + ubias + ib[6], acc[7][bb] + ubias + ib[7]);
        *(float4*)orow = s0;
        *(float4*)(orow + 4) = s1;
      } else {
#pragma unroll
        for (int a = 0; a < 8; a++)
          if (ibase + a < N_ITEMS) orow[a] = acc[a][bb] + ubias + ib[a];
      }
    }
  }
}

extern "C" void kernel_launch(void* const* d_in, const int* in_sizes, int n_in,
                              void* d_out, int out_size, void* d_ws, size_t ws_size,
                              hipStream_t stream) {
  const float* user_emb  = (const float*)d_in[0];
  const float* item_emb  = (const float*)d_in[1];
  const float* user_bias = (const float*)d_in[2];
  const float* item_bias = (const float*)d_in[3];
  const float* pop_emb   = (const float*)d_in[4];
  const float* uW1 = (const float*)d_in[5];
  const float* ub1 = (const float*)d_in[6];
  const float* uW2 = (const float*)d_in[7];
  const float* ub2 = (const float*)d_in[8];
  const float* iW1 = (const float*)d_in[9];
  const float* ib1 = (const float*)d_in[10];
  const float* iW2 = (const float*)d_in[11];
  const float* ib2 = (const float*)d_in[12];
  const float* gW1 = (const float*)d_in[13];
  const float* gb1 = (const float*)d_in[14];
  const float* gW2 = (const float*)d_in[15];
  const float* gb2 = (const float*)d_in[16];
  const float* adj_vals = (const float*)d_in[17];
  const int* adj_rows = (const int*)d_in[18];
  const int* adj_cols = (const int*)d_in[19];
  const int* bins  = (const int*)d_in[20];
  const int* users = (const int*)d_in[21];
  float* out = (float*)d_out;

  // workspace layout (float offsets); high-water 33,122,640
  float* ws = (float*)d_ws;
  float* Oacc = ws;                    // 9,600,000
  float* bufA = ws + 9600000;          // 9,600,000
  float* bufB = ws + 19200000;         // 9,600,000 (strided gstage)
  uint2* epack = (uint2*)(ws + 28800000);      // 2M uint2 -> ends 32,800,000
  int* rowbeg = (int*)(ws + 32800000);         // 150,000 -> 32,950,000
  int* rowend = (int*)(ws + 32950000);         // 150,000 -> 33,100,000
  // control ints: contiguous for a single memset
  int* uflag   = (int*)(ws + 33100000);        // 3,125 (bitmask)
  int* ucnt    = (int*)(ws + 33103125);        // 1
  int* bcur    = (int*)(ws + 33103126);        // 293
  int* gcursor = (int*)(ws + 33103419);        // 1
  int* ulist   = (int*)(ws + 33103420);        // 256 -> ends 33,103,676
  float* Ut   = ws + 33104000;                 // 16,640 -> 33,120,640
  float* hp   = ws + 33121000;                 // 640
  float* pp1  = ws + 33122000;                 // 640
  uint2* gstage = (uint2*)bufB;                // 293*8192*8B = 19.2 MB
  __half* Eh0 = (__half*)bufA;                 // emb fp16; dead after spmm1
  __half* E1h = (__half*)(bufA + 4800000);     // layer1 out; dead after spmm2
  __half* E2h = (__half*)bufB;                 // layer2 out (gstage dead)
  float* I  = bufB;                            // 3,200,000 (E2h dead by then)

  hipMemsetAsync(uflag, 0, 3680 * sizeof(int), stream);  // uflag..ulist
  k_prep<<<9376, 256, 0, stream>>>(user_emb, item_emb, Eh0, pop_emb, gW1, iW1, hp, pp1);
  k_p1<<<P1_BLOCKS, 256, 0, stream>>>(adj_rows, adj_cols, adj_vals, bcur, gstage);
  k_p2<<<NB2 + 1, 512, 0, stream>>>(bcur, gstage, epack, rowbeg, rowend, gcursor,
                                    users, uflag, ulist, ucnt);

  k_spmm1<<<37500, 256, 0, stream>>>(rowbeg, rowend, epack, user_emb, item_emb,
                                     Eh0, uflag, E1h, Oacc);
  k_spmm2h<<<37500, 256, 0, stream>>>(rowbeg, rowend, epack, E1h, uflag, E2h, Oacc);
  k_spmm3h<<<12564, 256, 0, stream>>>(rowbeg, rowend, epack, E2h, ulist, ucnt, Oacc);

  k_user<<<64, 256, 0, stream>>>(Oacc, users, user_bias, uW1, ub1, uW2, ub2, Ut);
  k_gemm12<<<391, 256, 0, stream>>>(Oacc, gW1, iW1, bins, hp, pp1, gb1, gW2, gb2,
                                    ib1, iW2, ib2, I);
  k_scores<<<391, 256, 0, stream>>>(I, Ut, item_bias, out);
}